// Round 10
// baseline (346.077 us; speedup 1.0000x reference)
//
#include <hip/hip_runtime.h>
#include <math.h>

#define N_NODES 100000
#define N_EDGES 1600000
#define F 128

// CSR radix: buckets of 256 destination nodes, fixed-capacity segments
#define BSH 8
#define NBUCK 391          // ceil(100000 / 256)
#define BCAP 5120          // per-bucket capacity (mean 4096, +16 sigma)
#define PB_EDGES 2048      // edges per part block
#define NB_PART 782        // part blocks (ceil(1.6M/2048))
#define NB_SCORES 1563     // score blocks (64 nodes/block, 16 nodes/wave)
#define NB_COLLECT 392     // collect blocks in fused mid kernel

typedef unsigned int u32;
typedef unsigned short u16;
typedef __attribute__((ext_vector_type(8))) short short8;
typedef __attribute__((ext_vector_type(4))) float floatx4;
typedef __attribute__((ext_vector_type(2))) float f32x2;
typedef __attribute__((ext_vector_type(4))) u32 u32x4;

// ---------------- helpers ----------------

__device__ __forceinline__ u32 key_of(float s) {
    u32 u = __float_as_uint(s);
    return (u & 0x80000000u) ? ~u : (u | 0x80000000u);   // larger float -> larger key
}

__device__ __forceinline__ float wave_reduce(float v) {
    #pragma unroll
    for (int off = 32; off > 0; off >>= 1) v += __shfl_down(v, off, 64);
    return v;
}

__device__ __forceinline__ u16 f2bf(float f) {   // round-to-nearest-even
    u32 u = __float_as_uint(f);
    u += 0x7fffu + ((u >> 16) & 1u);
    return (u16)(u >> 16);
}

__device__ __forceinline__ float bflo(u32 b) { return __uint_as_float(b << 16); }
__device__ __forceinline__ float bfhi(u32 b) { return __uint_as_float(b & 0xffff0000u); }

// packed fp32 accumulate: acc.{x,y} += {lo,hi bf16 of u}
__device__ __forceinline__ void pk_acc(f32x2& acc, u32 u) {
    f32x2 v; v.x = bflo(u); v.y = bfhi(u);
    asm("v_pk_add_f32 %0, %1, %0" : "+v"(acc) : "v"(v));
}
__device__ __forceinline__ void pk_add2(f32x2& a, f32x2 b) {
    asm("v_pk_add_f32 %0, %1, %0" : "+v"(a) : "v"(b));
}

// ---------------- 1a. edge partition (radix into 256-node buckets) -----------------
// Solo kernel this round: attribution probe for the front chain.

__global__ __launch_bounds__(256) void k_part(const int* __restrict__ ei,
                                              u32* __restrict__ gcur,
                                              u32* __restrict__ pairs) {
    __shared__ u32 lh[NBUCK];     // local histogram, then local cursor
    __shared__ u32 lbase[NBUCK];  // reserved base within bucket segment
    int t = threadIdx.x;
    int e0 = blockIdx.x * PB_EDGES;
    int e1 = e0 + PB_EDGES; if (e1 > N_EDGES) e1 = N_EDGES;
    for (int i = t; i < NBUCK; i += 256) lh[i] = 0u;
    __syncthreads();
    for (int e = e0 + t; e < e1; e += 256)
        atomicAdd(&lh[((u32)ei[N_EDGES + e]) >> BSH], 1u);
    __syncthreads();
    for (int b = t; b < NBUCK; b += 256) {
        u32 c = lh[b];
        lbase[b] = c ? atomicAdd(&gcur[b], c) : 0u;
        lh[b] = 0u;
    }
    __syncthreads();
    for (int e = e0 + t; e < e1; e += 256) {
        u32 d = (u32)ei[N_EDGES + e];
        u32 b = d >> BSH;
        u32 pos = lbase[b] + atomicAdd(&lh[b], 1u);
        pairs[(size_t)b * BCAP + pos] = ((d & 255u) << 17) | (u32)ei[e];
    }
}

// ---------------- 1b. scores (+bf16 x copy), 16 nodes/wave -------------------------

__global__ __launch_bounds__(256) void k_scores(const float* __restrict__ x,
                                                const float* __restrict__ p,
                                                float* __restrict__ scores,
                                                u32* __restrict__ hist16,
                                                u32* __restrict__ xb) {
    int sb = blockIdx.x;
    int wave = threadIdx.x >> 6;
    int lane = threadIdx.x & 63;
    int q = lane >> 4, sub = lane & 15;
    int nb0 = sb * 64 + wave * 16 + q;      // node for round r: nb0 + r*4
    float4 p0 = *(const float4*)&p[sub * 8];
    float4 p1 = *(const float4*)&p[sub * 8 + 4];
    float4 v0[4], v1[4];
    if (nb0 + 12 < N_NODES) {               // fast path: unguarded, loads hoist
        #pragma unroll
        for (int r = 0; r < 4; r++) {
            const float* xr = &x[(size_t)(nb0 + r * 4) * F + sub * 8];
            v0[r] = *(const float4*)xr;
            v1[r] = *(const float4*)(xr + 4);
        }
    } else {
        #pragma unroll
        for (int r = 0; r < 4; r++) {
            int node = nb0 + r * 4;
            v0[r] = make_float4(0.f, 0.f, 0.f, 0.f);
            v1[r] = make_float4(0.f, 0.f, 0.f, 0.f);
            if (node < N_NODES) {
                const float* xr = &x[(size_t)node * F + sub * 8];
                v0[r] = *(const float4*)xr;
                v1[r] = *(const float4*)(xr + 4);
            }
        }
    }
    #pragma unroll
    for (int r = 0; r < 4; r++) {
        int node = nb0 + r * 4;
        if (node >= N_NODES) continue;
        if (xb) {   // bf16 row-major copy of x for k_gemm_xb (L2/L3-resident)
            u32x4 pk;
            pk.x = (u32)f2bf(v0[r].x) | ((u32)f2bf(v0[r].y) << 16);
            pk.y = (u32)f2bf(v0[r].z) | ((u32)f2bf(v0[r].w) << 16);
            pk.z = (u32)f2bf(v1[r].x) | ((u32)f2bf(v1[r].y) << 16);
            pk.w = (u32)f2bf(v1[r].z) | ((u32)f2bf(v1[r].w) << 16);
            *(u32x4*)&xb[(size_t)node * 64 + sub * 4] = pk;
        }
        float d = v0[r].x * p0.x + v0[r].y * p0.y + v0[r].z * p0.z + v0[r].w * p0.w
                + v1[r].x * p1.x + v1[r].y * p1.y + v1[r].z * p1.z + v1[r].w * p1.w;
        #pragma unroll
        for (int off = 1; off < 16; off <<= 1) d += __shfl_xor(d, off, 64);
        if (sub == 0) {
            scores[node] = d;
            atomicAdd(&hist16[key_of(d) >> 16], 1u);
        }
    }
}

// ---------------- 2. block 0: top-128 threshold | block 1: gcur prefix scan --------

__global__ __launch_bounds__(1024) void k_scan16(const u32* __restrict__ hist16,
                                                 u32* __restrict__ state,
                                                 const u32* __restrict__ gcur,
                                                 u32* __restrict__ bbase) {
    __shared__ u32 a[1024];
    int t = threadIdx.x;
    if (blockIdx.x == 0) {
        const uint4* h4 = (const uint4*)hist16;
        u32 local = 0;
        #pragma unroll
        for (int i = 0; i < 16; i++) {
            uint4 v = h4[t * 16 + i];
            local += v.x + v.y + v.z + v.w;
        }
        a[t] = local;
        __syncthreads();
        for (int off = 1; off < 1024; off <<= 1) {
            u32 add = (t + off < 1024) ? a[t + off] : 0u;
            __syncthreads();
            a[t] += add;
            __syncthreads();
        }
        u32 S_above = (t == 1023) ? 0u : a[t + 1];
        if (S_above < 128u && a[t] >= 128u) {     // threshold bucket in my chunk
            u32 cum = S_above;
            for (int v = t * 64 + 63; v >= t * 64; v--) {
                cum += hist16[v];
                if (cum >= 128u) { state[0] = (u32)v; break; }
            }
        }
    } else {
        u32 v = (t < NBUCK) ? gcur[t] : 0u;
        a[t] = v;
        __syncthreads();
        for (int off = 1; off < 1024; off <<= 1) {
            u32 add = (t >= off) ? a[t - off] : 0u;
            __syncthreads();
            a[t] += add;
            __syncthreads();
        }
        if (t < NBUCK) bbase[t] = a[t] - v;       // exclusive prefix
    }
}

// ---------------- 2b. fused mid: candidate collect | CSR finalize ------------------

__global__ __launch_bounds__(256) void k_mid(const float* __restrict__ scores,
                                             u32* __restrict__ state,
                                             u32* __restrict__ cand,
                                             const u32* __restrict__ pairs,
                                             const u32* __restrict__ gcur,
                                             const u32* __restrict__ bbase,
                                             u32* __restrict__ offs,
                                             float* __restrict__ dinv,
                                             u32* __restrict__ ebuf) {
    if (blockIdx.x < NB_COLLECT) {
        u32 T = state[0] << 16;
        int i = blockIdx.x * 256 + threadIdx.x;
        if (i < N_NODES) {
            if (key_of(scores[i]) >= T) {
                u32 pos = atomicAdd(&state[2], 1u);
                if (pos < 2048u) cand[pos] = (u32)i;
            }
        }
    } else {
        __shared__ u32 h[256];
        __shared__ u32 sc[256];
        int b = blockIdx.x - NB_COLLECT, t = threadIdx.x;
        u32 base = bbase[b];
        u32 cnt  = gcur[b];
        const u32* seg = pairs + (size_t)b * BCAP;
        u32 lo = (u32)b << BSH;
        h[t] = 0u;
        __syncthreads();
        for (u32 i = t; i < cnt; i += 256)
            atomicAdd(&h[seg[i] >> 17], 1u);
        __syncthreads();
        sc[t] = h[t];
        __syncthreads();
        for (int off = 1; off < 256; off <<= 1) {
            u32 v = (t >= off) ? sc[t - off] : 0u;
            __syncthreads();
            sc[t] += v;
            __syncthreads();
        }
        int nn = N_NODES - (int)lo;     // >=256 except last bucket (160)
        if (t < nn) {
            u32 c = h[t];
            offs[lo + t] = base + (sc[t] - c);
            dinv[lo + t] = rsqrtf((float)c + 1.0f);
        }
        u32 excl = sc[t] - h[t];
        __syncthreads();
        sc[t] = excl;
        __syncthreads();
        for (u32 i = t; i < cnt; i += 256) {
            u32 pr = seg[i];
            u32 pos = base + atomicAdd(&sc[pr >> 17], 1u);
            ebuf[pos] = pr & 0x1ffffu;
        }
        if (b == 0 && t == 0) offs[N_NODES] = N_EDGES;
    }
}

// ---------------- 3a. GRU GEMMs with FUSED top-128 selection -----------------------
// Each block redundantly recomputes the exact top-128 ranking from cand/scores
// in LDS (nc ~ 150 -> ~nc^2/256 compares/thread, trivial). Removes the serial
// 1-block k_assemble16 launch. Selection scratch aliases the Bs tile (staged
// after a barrier).

__global__ __launch_bounds__(256) void k_ggemm(const float* __restrict__ x,
                                               const float* __restrict__ W,
                                               const float* __restrict__ w_ih,
                                               const float* __restrict__ w_hh,
                                               const float* __restrict__ scores,
                                               const float* __restrict__ p,
                                               const u32* __restrict__ state,
                                               const u32* __restrict__ cand,
                                               float* __restrict__ G) {
    __shared__ float As[32][128];
    __shared__ float Bs[64][131];
    __shared__ u32 s_topi[128];
    __shared__ float s_gate[128];
    __shared__ float s_inv;
    int t = threadIdx.x;
    // --- selection scratch aliases Bs: ci = 2048 u32 (8 KB), csc = 2048 f32 (8 KB)
    u32*   ci  = (u32*)&Bs[0][0];
    float* csc = (float*)&Bs[16][0];     // byte offset 8384 >= 8192: no overlap
    if (t < 64) {
        float2 pv = *(const float2*)&p[t * 2];
        float d = pv.x * pv.x + pv.y * pv.y;
        d = wave_reduce(d);
        if (t == 0) s_inv = rsqrtf(d);
    }
    u32 nc = state[2]; if (nc > 2048u) nc = 2048u;
    for (u32 i = t; i < nc; i += 256) { u32 ix = cand[i]; ci[i] = ix; csc[i] = scores[ix]; }
    __syncthreads();
    for (u32 i = t; i < nc; i += 256) {
        u32 myk = key_of(csc[i]);
        u32 myi = ci[i];
        int rank = 0;
        for (u32 j = 0; j < nc; j++) {
            u32 ok = key_of(csc[j]);
            rank += (int)((ok > myk) || (ok == myk && ci[j] < myi));
        }
        if (rank < 128) {   // exact jax semantics: value desc, index asc on ties
            s_topi[rank] = myi;
            s_gate[rank] = tanhf(csc[i] * s_inv);
        }
    }
    __syncthreads();        // selection done; Bs free for staging

    int k0 = blockIdx.x * 32;
    int by = blockIdx.y;                // 0..11; <6 -> gi (w_ih, x_tilde), else gh
    int j0 = by * 64;
    bool is_gi = (by < 6);
    #pragma unroll
    for (int i = 0; i < 4; i++) {
        int l = t + i * 256;
        int row = l >> 5, c4 = l & 31;
        float4 v;
        if (is_gi) {
            u32 idx = s_topi[k0 + row];
            float gt = s_gate[k0 + row];
            v = *(const float4*)&x[(size_t)idx * F + c4 * 4];
            v.x *= gt; v.y *= gt; v.z *= gt; v.w *= gt;
        } else {
            v = *(const float4*)&W[(k0 + row) * F + c4 * 4];
        }
        *(float4*)&As[row][c4 * 4] = v;
    }
    const float* mat = is_gi ? w_ih : w_hh;
    int jbase = is_gi ? j0 : (j0 - 384);
    #pragma unroll
    for (int i = 0; i < 8; i++) {
        int l = t + i * 256;
        int row = l >> 5, c4 = l & 31;
        float4 v = *(const float4*)&mat[(jbase + row) * F + c4 * 4];
        Bs[row][c4 * 4 + 0] = v.x; Bs[row][c4 * 4 + 1] = v.y;
        Bs[row][c4 * 4 + 2] = v.z; Bs[row][c4 * 4 + 3] = v.w;
    }
    __syncthreads();
    int ty = t >> 5, tx = t & 31;
    float acc[4][2] = {};
    #pragma unroll 4
    for (int f = 0; f < 128; f++) {
        float b0 = Bs[tx * 2][f], b1 = Bs[tx * 2 + 1][f];
        #pragma unroll
        for (int i = 0; i < 4; i++) {
            float a = As[ty * 4 + i][f];
            acc[i][0] += a * b0;
            acc[i][1] += a * b1;
        }
    }
    #pragma unroll
    for (int i = 0; i < 4; i++) {
        int k = k0 + ty * 4 + i;
        G[(size_t)k * 768 + j0 + tx * 2 + 0] = acc[i][0];
        G[(size_t)k * 768 + j0 + tx * 2 + 1] = acc[i][1];
    }
}

// ---------------- 3b. pointwise GRU gates -> Wnew + fragment-ordered bf16 B --------

__global__ void k_gate(const float* __restrict__ G, const float* __restrict__ W,
                       const float* __restrict__ b_ih, const float* __restrict__ b_hh,
                       float* __restrict__ Wnew, u16* __restrict__ Bfrag) {
    int idx = blockIdx.x * blockDim.x + threadIdx.x;   // 16384
    int k = idx >> 7, h = idx & 127;
    const float* gk = &G[(size_t)k * 768];
    float gir = gk[h]       + b_ih[h];
    float giz = gk[128 + h] + b_ih[128 + h];
    float gin = gk[256 + h] + b_ih[256 + h];
    float ghr = gk[384 + h] + b_hh[h];
    float ghz = gk[512 + h] + b_hh[128 + h];
    float ghn = gk[640 + h] + b_hh[256 + h];
    float wv  = W[k * F + h];
    float rg = 1.0f / (1.0f + expf(-(gir + ghr)));
    float z  = 1.0f / (1.0f + expf(-(giz + ghz)));
    float n  = tanhf(gin + rg * ghn);
    float val = (1.0f - z) * n + z * wv;
    Wnew[k * F + h] = val;
    int nb = h >> 4, kc = k >> 5, q = (k >> 3) & 3, m = h & 15, jj = k & 7;
    Bfrag[(((nb * 4 + kc) * 64) + q * 16 + m) * 8 + jj] = f2bf(val);
}

// ---------------- 5. yw = dinv * (x @ W_new) : bf16 MFMA ---------------------------

__device__ __forceinline__ void gemm_core(u16* As, const u16* __restrict__ Bfrag,
                                          const float* __restrict__ dinv,
                                          u16* __restrict__ yw, int r0, int t) {
    int wv = t >> 6, lane = t & 63;
    int q = lane >> 4, m = lane & 15;
    floatx4 acc[8] = {};
    #pragma unroll
    for (int kc = 0; kc < 4; kc++) {
        short8 a = *(const short8*)&As[((wv * 4 + kc) * 64 + lane) * 8];
        #pragma unroll
        for (int nb = 0; nb < 8; nb++) {
            short8 bfr = *(const short8*)&Bfrag[((nb * 4 + kc) * 64 + lane) * 8];
            acc[nb] = __builtin_amdgcn_mfma_f32_16x16x32_bf16(a, bfr, acc[nb], 0, 0, 0);
        }
    }
    __syncthreads();   // done reading A-frags; reuse As as epilogue buffer

    float d[4];
    #pragma unroll
    for (int reg = 0; reg < 4; reg++) {
        int gr = r0 + wv * 16 + q * 4 + reg;
        d[reg] = (gr < N_NODES) ? dinv[gr] : 0.f;
    }
    #pragma unroll
    for (int nb = 0; nb < 8; nb++) {
        #pragma unroll
        for (int reg = 0; reg < 4; reg++) {
            int row = wv * 16 + q * 4 + reg;
            As[row * 132 + nb * 16 + m] = f2bf(acc[nb][reg] * d[reg]);
        }
    }
    __syncthreads();
    // coalesced store: thread t -> row t>>2, 32-col segment (t&3)*32 (64 B)
    {
        int row = t >> 2, segi = t & 3;
        int gr = r0 + row;
        if (gr < N_NODES) {
            const uint2* src = (const uint2*)&As[row * 132 + segi * 32];
            uint2* dst = (uint2*)&yw[(size_t)gr * F + segi * 32];
            #pragma unroll
            for (int i = 0; i < 8; i++) dst[i] = src[i];
        }
    }
}

// fallback path: stage fp32 x -> bf16 fragments
__global__ __launch_bounds__(256) void k_gemm(const float* __restrict__ x,
                                              const u16* __restrict__ Bfrag,
                                              const float* __restrict__ dinv,
                                              u16* __restrict__ yw) {
    __shared__ __align__(16) u16 As[8448];
    int t = threadIdx.x;
    int r0 = blockIdx.x * 64;
    #pragma unroll
    for (int i = 0; i < 8; i++) {
        int l = t + i * 256;              // 2048 float4s
        int row = l >> 5, c4 = l & 31;
        int f0 = c4 * 4;
        float4 v = {0.f, 0.f, 0.f, 0.f};
        if (r0 + row < N_NODES) v = *(const float4*)&x[(size_t)(r0 + row) * F + f0];
        int widx = (((row >> 4) * 4 + (f0 >> 5)) * 64 + ((f0 >> 3) & 3) * 16 + (row & 15)) * 8
                   + (f0 & 7);
        ushort4 s4;
        s4.x = f2bf(v.x); s4.y = f2bf(v.y); s4.z = f2bf(v.z); s4.w = f2bf(v.w);
        *(ushort4*)&As[widx] = s4;
    }
    __syncthreads();
    gemm_core(As, Bfrag, dinv, yw, r0, t);
}

// fast path: bf16 x copy -> conflict-free consumption-order staging
__global__ __launch_bounds__(256) void k_gemm_xb(const u32* __restrict__ xb,
                                                 const u16* __restrict__ Bfrag,
                                                 const float* __restrict__ dinv,
                                                 u16* __restrict__ yw) {
    __shared__ __align__(16) u16 As[8448];
    int t = threadIdx.x;
    int r0 = blockIdx.x * 64;
    #pragma unroll
    for (int i = 0; i < 4; i++) {
        int wdx = t + i * 256;            // 0..1023  = chunk*64 + lane
        int lane = wdx & 63, chunk = wdx >> 6;
        int kc = chunk & 3, rowhi = chunk >> 2;
        int q = lane >> 4, m = lane & 15;
        int row = rowhi * 16 + m;
        u32x4 v = {0u, 0u, 0u, 0u};
        if (r0 + row < N_NODES)
            v = *(const u32x4*)&xb[(size_t)(r0 + row) * 64 + kc * 16 + q * 4];
        *(u32x4*)&As[wdx * 8] = v;
    }
    __syncthreads();
    gemm_core(As, Bfrag, dinv, yw, r0, t);
}

// ---------------- 6. gather-aggregate + fused head (4-way split, ~16us each) -------

#define EDGE_GROUP(J) {                                                      \
    u32 r = ebuf[(J) + q];                                                   \
    uint4 bb = *(const uint4*)&yw32[(size_t)r * 64 + sub * 4];               \
    pk_acc(a01, bb.x); pk_acc(a23, bb.y);                                    \
    pk_acc(a45, bb.z); pk_acc(a67, bb.w); }

#define BFLY(A) {                                                            \
    f32x2 tb;                                                                \
    tb.x = __shfl_xor(A.x, 16, 64); tb.y = __shfl_xor(A.y, 16, 64);          \
    pk_add2(A, tb);                                                          \
    tb.x = __shfl_xor(A.x, 32, 64); tb.y = __shfl_xor(A.y, 32, 64);          \
    pk_add2(A, tb); }

__global__ void k_gather(const u32* __restrict__ yw32, const u32* __restrict__ offs,
                         const u32* __restrict__ ebuf, const float* __restrict__ dinv,
                         const float* __restrict__ conv_bias, const float* __restrict__ lin_w,
                         const float* __restrict__ lin_b, float* __restrict__ out,
                         int node0) {
    int c = node0 + blockIdx.x * 4 + (threadIdx.x >> 6);
    if (c >= N_NODES) return;
    int lane = threadIdx.x & 63;
    int q = lane >> 4, sub = lane & 15;
    u32 jbeg = offs[c], jend = offs[c + 1];
    f32x2 a01 = {0.f, 0.f}, a23 = {0.f, 0.f}, a45 = {0.f, 0.f}, a67 = {0.f, 0.f};
    u32 j = jbeg;
    for (; j + 16 <= jend; j += 16) {   // 16 edges (4 quad-groups) in flight
        EDGE_GROUP(j) EDGE_GROUP(j + 4) EDGE_GROUP(j + 8) EDGE_GROUP(j + 12)
    }
    for (; j + 4 <= jend; j += 4) EDGE_GROUP(j)
    u32 rem = jend - j;
    if (rem) {                           // 1..3 leftover edges, exec-masked adds
        u32 idx = ((u32)q < rem) ? (j + q) : j;
        u32 r = ebuf[idx];
        uint4 bb = *(const uint4*)&yw32[(size_t)r * 64 + sub * 4];
        if ((u32)q < rem) {
            pk_acc(a01, bb.x); pk_acc(a23, bb.y);
            pk_acc(a45, bb.z); pk_acc(a67, bb.w);
        }
    }
    BFLY(a01) BFLY(a23) BFLY(a45) BFLY(a67)
    float dc = dinv[c];
    uint4 sb = *(const uint4*)&yw32[(size_t)c * 64 + sub * 4];
    float4 cb0 = *(const float4*)&conv_bias[sub * 8];
    float4 cb1 = *(const float4*)&conv_bias[sub * 8 + 4];
    float4 lw0 = *(const float4*)&lin_w[sub * 8];
    float4 lw1 = *(const float4*)&lin_w[sub * 8 + 4];
    float h0 = fmaxf(dc * (a01.x + bflo(sb.x)) + cb0.x, 0.f);
    float h1 = fmaxf(dc * (a01.y + bfhi(sb.x)) + cb0.y, 0.f);
    float h2 = fmaxf(dc * (a23.x + bflo(sb.y)) + cb0.z, 0.f);
    float h3 = fmaxf(dc * (a23.y + bfhi(sb.y)) + cb0.w, 0.f);
    float h4 = fmaxf(dc * (a45.x + bflo(sb.z)) + cb1.x, 0.f);
    float h5 = fmaxf(dc * (a45.y + bfhi(sb.z)) + cb1.y, 0.f);
    float h6 = fmaxf(dc * (a67.x + bflo(sb.w)) + cb1.z, 0.f);
    float h7 = fmaxf(dc * (a67.y + bfhi(sb.w)) + cb1.w, 0.f);
    float part = (h0 * lw0.x + h1 * lw0.y + h2 * lw0.z + h3 * lw0.w)
               + (h4 * lw1.x + h5 * lw1.y + h6 * lw1.z + h7 * lw1.w);
    #pragma unroll
    for (int off = 8; off > 0; off >>= 1) part += __shfl_down(part, off, 64);
    if (lane == 0) out[c] = part + lin_b[0];
}

// ---------------- launch ----------------

extern "C" void kernel_launch(void* const* d_in, const int* in_sizes, int n_in,
                              void* d_out, int out_size, void* d_ws, size_t ws_size,
                              hipStream_t stream) {
    const float* x         = (const float*)d_in[0];
    const int*   ei        = (const int*)  d_in[1];
    const float* W         = (const float*)d_in[2];
    const float* p         = (const float*)d_in[3];
    const float* w_ih      = (const float*)d_in[4];
    const float* w_hh      = (const float*)d_in[5];
    const float* b_ih      = (const float*)d_in[6];
    const float* b_hh      = (const float*)d_in[7];
    const float* conv_bias = (const float*)d_in[8];
    const float* lin_w     = (const float*)d_in[9];
    const float* lin_b     = (const float*)d_in[10];
    float* out = (float*)d_out;

    u32*   w  = (u32*)d_ws;
    float* wf = (float*)d_ws;

    // ws layout (word offsets). G overlays PAIRS (pairs dead after k_mid). XB
    // (optional bf16 copy of x) appended past YW -> total 67.2 MB when enabled.
    const size_t SCORES_W = 0;          // 100000
    const size_t DINV_W   = 100096;     // 100000
    const size_t OFFS_W   = 200192;     // 100001
    const size_t HIST16_W = 300288;     // 65536
    const size_t STATE_W  = 365824;     // 8
    const size_t GCUR_W   = 365832;     // 391 (memset covers hist16..gcur)
    const size_t BBASE_W  = 366224;     // 391 (written by k_scan16 block 1)
    const size_t CAND_W   = 366616;     // 2048
    const size_t WNEW_W   = 368920;     // 16384
    const size_t BFRAG_W  = 385304;     // 4096 words (8192 u16)
    const size_t PAIRS_W  = 389400;     // 391 * 5120 = 2001920 words
    const size_t EBUF_W   = 2400000;    // 1600000
    const size_t YW_W     = 4000000;    // bf16 yw: 6400000 words
    const size_t XB_W     = 10400000;   // bf16 x copy: 6400000 words (optional)

    float* scores  = wf + SCORES_W;
    float* dinv    = wf + DINV_W;
    u32*   offs    = w  + OFFS_W;
    u32*   hist16  = w  + HIST16_W;
    u32*   state   = w  + STATE_W;
    u32*   gcur    = w  + GCUR_W;
    u32*   bbase   = w  + BBASE_W;
    u32*   cand    = w  + CAND_W;
    float* Wnew    = wf + WNEW_W;
    u16*   Bfrag   = (u16*)(w + BFRAG_W);
    u32*   pairs   = w  + PAIRS_W;
    float* G       = wf + PAIRS_W;      // overlay (pairs dead after k_mid)
    u32*   ebuf    = w  + EBUF_W;
    u16*   yw      = (u16*)(w + YW_W);
    u32*   yw32    = w + YW_W;

    bool   use_xb  = ws_size >= (XB_W + 6400000) * sizeof(u32);
    u32*   xb      = use_xb ? (w + XB_W) : (u32*)0;

    hipMemsetAsync(hist16, 0, (65536 + 8 + NBUCK) * sizeof(u32), stream);

    // --- L1a: edge partition (solo -- attribution probe)
    k_part<<<NB_PART, 256, 0, stream>>>(ei, gcur, pairs);
    // --- L1b: scores + bf16 x copy (solo)
    k_scores<<<NB_SCORES, 256, 0, stream>>>(x, p, scores, hist16, xb);
    // --- L2: threshold-bucket scan | gcur prefix scan -> bbase
    k_scan16<<<2, 1024, 0, stream>>>(hist16, state, gcur, bbase);
    // --- L3: candidate collect | CSR finalize (bbase precomputed)
    k_mid<<<NB_COLLECT + NBUCK, 256, 0, stream>>>(scores, state, cand, pairs, gcur,
                                                  bbase, offs, dinv, ebuf);
    // --- GRU -> W_new (top-128 selection fused into each ggemm block)
    k_ggemm<<<dim3(4, 12), 256, 0, stream>>>(x, W, w_ih, w_hh, scores, p, state,
                                             cand, G);
    k_gate<<<64, 256, 0, stream>>>(G, W, b_ih, b_hh, Wnew, Bfrag);

    // --- yw = dinv * (x @ W_new)  (bf16 MFMA)
    if (use_xb) k_gemm_xb<<<1563, 256, 0, stream>>>(xb, Bfrag, dinv, yw);
    else        k_gemm   <<<1563, 256, 0, stream>>>(x,  Bfrag, dinv, yw);

    // --- gather + fused head (4 quarter-range launches)
    k_gather<<<6250, 256, 0, stream>>>(yw32, offs, ebuf, dinv, conv_bias, lin_w,
                                       lin_b, out, 0);
    k_gather<<<6250, 256, 0, stream>>>(yw32, offs, ebuf, dinv, conv_bias, lin_w,
                                       lin_b, out, 25000);
    k_gather<<<6250, 256, 0, stream>>>(yw32, offs, ebuf, dinv, conv_bias, lin_w,
                                       lin_b, out, 50000);
    k_gather<<<6250, 256, 0, stream>>>(yw32, offs, ebuf, dinv, conv_bias, lin_w,
                                       lin_b, out, 75000);
}

// Round 11
// 298.560 us; speedup vs baseline: 1.1592x; 1.1592x over previous
//
#include <hip/hip_runtime.h>
#include <math.h>

#define N_NODES 100000
#define N_EDGES 1600000
#define F 128

// CSR radix: buckets of 256 destination nodes, fixed-capacity segments
#define BSH 8
#define NBUCK 391          // ceil(100000 / 256)
#define BCAP 5120          // per-bucket capacity (mean 4096, +16 sigma)
#define PB_EDGES 2048      // edges per part block
#define NB_PART 782        // part blocks (ceil(1.6M/2048)) -- dispatched FIRST
#define NB_SCORES 1563     // score blocks (64 nodes/block, 16 nodes/wave)
#define NB_COLLECT 392     // collect blocks in fused mid kernel

typedef unsigned int u32;
typedef unsigned short u16;
typedef __attribute__((ext_vector_type(8))) short short8;
typedef __attribute__((ext_vector_type(4))) float floatx4;
typedef __attribute__((ext_vector_type(2))) float f32x2;

// ---------------- helpers ----------------

__device__ __forceinline__ u32 key_of(float s) {
    u32 u = __float_as_uint(s);
    return (u & 0x80000000u) ? ~u : (u | 0x80000000u);   // larger float -> larger key
}

__device__ __forceinline__ float wave_reduce(float v) {
    #pragma unroll
    for (int off = 32; off > 0; off >>= 1) v += __shfl_down(v, off, 64);
    return v;
}

__device__ __forceinline__ u16 f2bf(float f) {   // round-to-nearest-even
    u32 u = __float_as_uint(f);
    u += 0x7fffu + ((u >> 16) & 1u);
    return (u16)(u >> 16);
}

__device__ __forceinline__ float bflo(u32 b) { return __uint_as_float(b << 16); }
__device__ __forceinline__ float bfhi(u32 b) { return __uint_as_float(b & 0xffff0000u); }

// packed fp32 accumulate: acc.{x,y} += {lo,hi bf16 of u}
__device__ __forceinline__ void pk_acc(f32x2& acc, u32 u) {
    f32x2 v; v.x = bflo(u); v.y = bfhi(u);
    asm("v_pk_add_f32 %0, %1, %0" : "+v"(acc) : "v"(v));
}
__device__ __forceinline__ void pk_add2(f32x2& a, f32x2 b) {
    asm("v_pk_add_f32 %0, %1, %0" : "+v"(a) : "v"(b));
}

// ---------------- 1. fused front: edge partition (first) | scores -----------------
// launch_bounds(256,4): VGPR cap 128 (not the default-heuristic 32) so the score
// branch's 8 independent 16B loads can actually stay in flight (r10 probe: solo
// k_scores had VGPR=32 -> serialized load chain -> 0.9 TB/s latency-bound).
// No xb copy: dropped (was +25.6MB of writes on this critical branch).

__global__ __launch_bounds__(256, 4)
void k_front(const float* __restrict__ x, const float* __restrict__ p,
             const int* __restrict__ ei, float* __restrict__ scores,
             u32* __restrict__ hist16, u32* __restrict__ gcur,
             u32* __restrict__ pairs) {
    if (blockIdx.x < NB_PART) {
        // ---- radix partition of edges into 256-node destination buckets
        __shared__ u32 lh[NBUCK];     // local histogram, then local cursor
        __shared__ u32 lbase[NBUCK];  // reserved base within bucket segment
        int t = threadIdx.x;
        int e0 = blockIdx.x * PB_EDGES;
        int e1 = e0 + PB_EDGES; if (e1 > N_EDGES) e1 = N_EDGES;
        for (int i = t; i < NBUCK; i += 256) lh[i] = 0u;
        __syncthreads();
        for (int e = e0 + t; e < e1; e += 256)
            atomicAdd(&lh[((u32)ei[N_EDGES + e]) >> BSH], 1u);
        __syncthreads();
        for (int b = t; b < NBUCK; b += 256) {
            u32 c = lh[b];
            lbase[b] = c ? atomicAdd(&gcur[b], c) : 0u;
            lh[b] = 0u;
        }
        __syncthreads();
        for (int e = e0 + t; e < e1; e += 256) {
            u32 d = (u32)ei[N_EDGES + e];
            u32 b = d >> BSH;
            u32 pos = lbase[b] + atomicAdd(&lh[b], 1u);
            pairs[(size_t)b * BCAP + pos] = ((d & 255u) << 17) | (u32)ei[e];
        }
    } else {
        // ---- scores: 16 nodes per wave (16 lanes per node, 4 rounds)
        int sb = blockIdx.x - NB_PART;
        int wave = threadIdx.x >> 6;
        int lane = threadIdx.x & 63;
        int q = lane >> 4, sub = lane & 15;
        int nb0 = sb * 64 + wave * 16 + q;      // node for round r: nb0 + r*4
        float4 p0 = *(const float4*)&p[sub * 8];
        float4 p1 = *(const float4*)&p[sub * 8 + 4];
        if (nb0 + 12 < N_NODES) {
            // fast path: 8 named loads issued before ANY consumption (true MLP)
            const float* x0 = &x[(size_t)(nb0     ) * F + sub * 8];
            const float* x1 = &x[(size_t)(nb0 +  4) * F + sub * 8];
            const float* x2 = &x[(size_t)(nb0 +  8) * F + sub * 8];
            const float* x3 = &x[(size_t)(nb0 + 12) * F + sub * 8];
            float4 a0 = *(const float4*)x0;
            float4 b0 = *(const float4*)(x0 + 4);
            float4 a1 = *(const float4*)x1;
            float4 b1 = *(const float4*)(x1 + 4);
            float4 a2 = *(const float4*)x2;
            float4 b2 = *(const float4*)(x2 + 4);
            float4 a3 = *(const float4*)x3;
            float4 b3 = *(const float4*)(x3 + 4);
            float d0 = a0.x * p0.x + a0.y * p0.y + a0.z * p0.z + a0.w * p0.w
                     + b0.x * p1.x + b0.y * p1.y + b0.z * p1.z + b0.w * p1.w;
            float d1 = a1.x * p0.x + a1.y * p0.y + a1.z * p0.z + a1.w * p0.w
                     + b1.x * p1.x + b1.y * p1.y + b1.z * p1.z + b1.w * p1.w;
            float d2 = a2.x * p0.x + a2.y * p0.y + a2.z * p0.z + a2.w * p0.w
                     + b2.x * p1.x + b2.y * p1.y + b2.z * p1.z + b2.w * p1.w;
            float d3 = a3.x * p0.x + a3.y * p0.y + a3.z * p0.z + a3.w * p0.w
                     + b3.x * p1.x + b3.y * p1.y + b3.z * p1.z + b3.w * p1.w;
            #pragma unroll
            for (int off = 1; off < 16; off <<= 1) {
                d0 += __shfl_xor(d0, off, 64);
                d1 += __shfl_xor(d1, off, 64);
                d2 += __shfl_xor(d2, off, 64);
                d3 += __shfl_xor(d3, off, 64);
            }
            if (sub == 0) {
                scores[nb0]      = d0;
                scores[nb0 + 4]  = d1;
                scores[nb0 + 8]  = d2;
                scores[nb0 + 12] = d3;
                atomicAdd(&hist16[key_of(d0) >> 16], 1u);
                atomicAdd(&hist16[key_of(d1) >> 16], 1u);
                atomicAdd(&hist16[key_of(d2) >> 16], 1u);
                atomicAdd(&hist16[key_of(d3) >> 16], 1u);
            }
        } else {
            #pragma unroll
            for (int r = 0; r < 4; r++) {
                int node = nb0 + r * 4;
                if (node >= N_NODES) continue;
                const float* xr = &x[(size_t)node * F + sub * 8];
                float4 v0 = *(const float4*)xr;
                float4 v1 = *(const float4*)(xr + 4);
                float d = v0.x * p0.x + v0.y * p0.y + v0.z * p0.z + v0.w * p0.w
                        + v1.x * p1.x + v1.y * p1.y + v1.z * p1.z + v1.w * p1.w;
                #pragma unroll
                for (int off = 1; off < 16; off <<= 1) d += __shfl_xor(d, off, 64);
                if (sub == 0) {
                    scores[node] = d;
                    atomicAdd(&hist16[key_of(d) >> 16], 1u);
                }
            }
        }
    }
}

// ---------------- 2. block 0: top-128 threshold | block 1: gcur prefix scan --------

__global__ __launch_bounds__(1024) void k_scan16(const u32* __restrict__ hist16,
                                                 u32* __restrict__ state,
                                                 const u32* __restrict__ gcur,
                                                 u32* __restrict__ bbase) {
    __shared__ u32 a[1024];
    int t = threadIdx.x;
    if (blockIdx.x == 0) {
        const uint4* h4 = (const uint4*)hist16;
        u32 local = 0;
        #pragma unroll
        for (int i = 0; i < 16; i++) {
            uint4 v = h4[t * 16 + i];
            local += v.x + v.y + v.z + v.w;
        }
        a[t] = local;
        __syncthreads();
        for (int off = 1; off < 1024; off <<= 1) {
            u32 add = (t + off < 1024) ? a[t + off] : 0u;
            __syncthreads();
            a[t] += add;
            __syncthreads();
        }
        u32 S_above = (t == 1023) ? 0u : a[t + 1];
        if (S_above < 128u && a[t] >= 128u) {     // threshold bucket in my chunk
            u32 cum = S_above;
            for (int v = t * 64 + 63; v >= t * 64; v--) {
                cum += hist16[v];
                if (cum >= 128u) { state[0] = (u32)v; break; }
            }
        }
    } else {
        u32 v = (t < NBUCK) ? gcur[t] : 0u;
        a[t] = v;
        __syncthreads();
        for (int off = 1; off < 1024; off <<= 1) {
            u32 add = (t >= off) ? a[t - off] : 0u;
            __syncthreads();
            a[t] += add;
            __syncthreads();
        }
        if (t < NBUCK) bbase[t] = a[t] - v;       // exclusive prefix
    }
}

// ---------------- 2b. fused mid: candidate collect | CSR finalize ------------------

__global__ __launch_bounds__(256) void k_mid(const float* __restrict__ scores,
                                             u32* __restrict__ state,
                                             u32* __restrict__ cand,
                                             const u32* __restrict__ pairs,
                                             const u32* __restrict__ gcur,
                                             const u32* __restrict__ bbase,
                                             u32* __restrict__ offs,
                                             float* __restrict__ dinv,
                                             u32* __restrict__ ebuf) {
    if (blockIdx.x < NB_COLLECT) {
        u32 T = state[0] << 16;
        int i = blockIdx.x * 256 + threadIdx.x;
        if (i < N_NODES) {
            if (key_of(scores[i]) >= T) {
                u32 pos = atomicAdd(&state[2], 1u);
                if (pos < 2048u) cand[pos] = (u32)i;
            }
        }
    } else {
        __shared__ u32 h[256];
        __shared__ u32 sc[256];
        int b = blockIdx.x - NB_COLLECT, t = threadIdx.x;
        u32 base = bbase[b];
        u32 cnt  = gcur[b];
        const u32* seg = pairs + (size_t)b * BCAP;
        u32 lo = (u32)b << BSH;
        h[t] = 0u;
        __syncthreads();
        for (u32 i = t; i < cnt; i += 256)
            atomicAdd(&h[seg[i] >> 17], 1u);
        __syncthreads();
        sc[t] = h[t];
        __syncthreads();
        for (int off = 1; off < 256; off <<= 1) {
            u32 v = (t >= off) ? sc[t - off] : 0u;
            __syncthreads();
            sc[t] += v;
            __syncthreads();
        }
        int nn = N_NODES - (int)lo;     // >=256 except last bucket (160)
        if (t < nn) {
            u32 c = h[t];
            offs[lo + t] = base + (sc[t] - c);
            dinv[lo + t] = rsqrtf((float)c + 1.0f);
        }
        u32 excl = sc[t] - h[t];
        __syncthreads();
        sc[t] = excl;
        __syncthreads();
        for (u32 i = t; i < cnt; i += 256) {
            u32 pr = seg[i];
            u32 pos = base + atomicAdd(&sc[pr >> 17], 1u);
            ebuf[pos] = pr & 0x1ffffu;
        }
        if (b == 0 && t == 0) offs[N_NODES] = N_EDGES;
    }
}

// ---------------- 3a. GRU GEMMs with FUSED top-128 selection -----------------------
// Each block redundantly recomputes the exact top-128 ranking from cand/scores
// in LDS (nc ~ 150 -> trivial). Selection scratch aliases the Bs tile.

__global__ __launch_bounds__(256) void k_ggemm(const float* __restrict__ x,
                                               const float* __restrict__ W,
                                               const float* __restrict__ w_ih,
                                               const float* __restrict__ w_hh,
                                               const float* __restrict__ scores,
                                               const float* __restrict__ p,
                                               const u32* __restrict__ state,
                                               const u32* __restrict__ cand,
                                               float* __restrict__ G) {
    __shared__ float As[32][128];
    __shared__ float Bs[64][131];
    __shared__ u32 s_topi[128];
    __shared__ float s_gate[128];
    __shared__ float s_inv;
    int t = threadIdx.x;
    u32*   ci  = (u32*)&Bs[0][0];
    float* csc = (float*)&Bs[16][0];     // byte offset 8384 >= 8192: no overlap
    if (t < 64) {
        float2 pv = *(const float2*)&p[t * 2];
        float d = pv.x * pv.x + pv.y * pv.y;
        d = wave_reduce(d);
        if (t == 0) s_inv = rsqrtf(d);
    }
    u32 nc = state[2]; if (nc > 2048u) nc = 2048u;
    for (u32 i = t; i < nc; i += 256) { u32 ix = cand[i]; ci[i] = ix; csc[i] = scores[ix]; }
    __syncthreads();
    for (u32 i = t; i < nc; i += 256) {
        u32 myk = key_of(csc[i]);
        u32 myi = ci[i];
        int rank = 0;
        for (u32 j = 0; j < nc; j++) {
            u32 ok = key_of(csc[j]);
            rank += (int)((ok > myk) || (ok == myk && ci[j] < myi));
        }
        if (rank < 128) {   // exact jax semantics: value desc, index asc on ties
            s_topi[rank] = myi;
            s_gate[rank] = tanhf(csc[i] * s_inv);
        }
    }
    __syncthreads();        // selection done; Bs free for staging

    int k0 = blockIdx.x * 32;
    int by = blockIdx.y;                // 0..11; <6 -> gi (w_ih, x_tilde), else gh
    int j0 = by * 64;
    bool is_gi = (by < 6);
    #pragma unroll
    for (int i = 0; i < 4; i++) {
        int l = t + i * 256;
        int row = l >> 5, c4 = l & 31;
        float4 v;
        if (is_gi) {
            u32 idx = s_topi[k0 + row];
            float gt = s_gate[k0 + row];
            v = *(const float4*)&x[(size_t)idx * F + c4 * 4];
            v.x *= gt; v.y *= gt; v.z *= gt; v.w *= gt;
        } else {
            v = *(const float4*)&W[(k0 + row) * F + c4 * 4];
        }
        *(float4*)&As[row][c4 * 4] = v;
    }
    const float* mat = is_gi ? w_ih : w_hh;
    int jbase = is_gi ? j0 : (j0 - 384);
    #pragma unroll
    for (int i = 0; i < 8; i++) {
        int l = t + i * 256;
        int row = l >> 5, c4 = l & 31;
        float4 v = *(const float4*)&mat[(jbase + row) * F + c4 * 4];
        Bs[row][c4 * 4 + 0] = v.x; Bs[row][c4 * 4 + 1] = v.y;
        Bs[row][c4 * 4 + 2] = v.z; Bs[row][c4 * 4 + 3] = v.w;
    }
    __syncthreads();
    int ty = t >> 5, tx = t & 31;
    float acc[4][2] = {};
    #pragma unroll 4
    for (int f = 0; f < 128; f++) {
        float b0 = Bs[tx * 2][f], b1 = Bs[tx * 2 + 1][f];
        #pragma unroll
        for (int i = 0; i < 4; i++) {
            float a = As[ty * 4 + i][f];
            acc[i][0] += a * b0;
            acc[i][1] += a * b1;
        }
    }
    #pragma unroll
    for (int i = 0; i < 4; i++) {
        int k = k0 + ty * 4 + i;
        G[(size_t)k * 768 + j0 + tx * 2 + 0] = acc[i][0];
        G[(size_t)k * 768 + j0 + tx * 2 + 1] = acc[i][1];
    }
}

// ---------------- 3b. pointwise GRU gates -> Wnew + fragment-ordered bf16 B --------

__global__ void k_gate(const float* __restrict__ G, const float* __restrict__ W,
                       const float* __restrict__ b_ih, const float* __restrict__ b_hh,
                       float* __restrict__ Wnew, u16* __restrict__ Bfrag) {
    int idx = blockIdx.x * blockDim.x + threadIdx.x;   // 16384
    int k = idx >> 7, h = idx & 127;
    const float* gk = &G[(size_t)k * 768];
    float gir = gk[h]       + b_ih[h];
    float giz = gk[128 + h] + b_ih[128 + h];
    float gin = gk[256 + h] + b_ih[256 + h];
    float ghr = gk[384 + h] + b_hh[h];
    float ghz = gk[512 + h] + b_hh[128 + h];
    float ghn = gk[640 + h] + b_hh[256 + h];
    float wv  = W[k * F + h];
    float rg = 1.0f / (1.0f + expf(-(gir + ghr)));
    float z  = 1.0f / (1.0f + expf(-(giz + ghz)));
    float n  = tanhf(gin + rg * ghn);
    float val = (1.0f - z) * n + z * wv;
    Wnew[k * F + h] = val;
    int nb = h >> 4, kc = k >> 5, q = (k >> 3) & 3, m = h & 15, jj = k & 7;
    Bfrag[(((nb * 4 + kc) * 64) + q * 16 + m) * 8 + jj] = f2bf(val);
}

// ---------------- 5. yw = dinv * (x @ W_new) : bf16 MFMA ---------------------------
// fp32-staging path (round-0 proven). MFMA + LDS-transposed coalesced epilogue.

__global__ __launch_bounds__(256) void k_gemm(const float* __restrict__ x,
                                              const u16* __restrict__ Bfrag,
                                              const float* __restrict__ dinv,
                                              u16* __restrict__ yw) {
    __shared__ __align__(16) u16 As[8448];
    int t = threadIdx.x;
    int r0 = blockIdx.x * 64;
    #pragma unroll
    for (int i = 0; i < 8; i++) {
        int l = t + i * 256;              // 2048 float4s
        int row = l >> 5, c4 = l & 31;
        int f0 = c4 * 4;
        float4 v = {0.f, 0.f, 0.f, 0.f};
        if (r0 + row < N_NODES) v = *(const float4*)&x[(size_t)(r0 + row) * F + f0];
        int widx = (((row >> 4) * 4 + (f0 >> 5)) * 64 + ((f0 >> 3) & 3) * 16 + (row & 15)) * 8
                   + (f0 & 7);
        ushort4 s4;
        s4.x = f2bf(v.x); s4.y = f2bf(v.y); s4.z = f2bf(v.z); s4.w = f2bf(v.w);
        *(ushort4*)&As[widx] = s4;
    }
    __syncthreads();

    int wv = t >> 6, lane = t & 63;
    int q = lane >> 4, m = lane & 15;
    floatx4 acc[8] = {};
    #pragma unroll
    for (int kc = 0; kc < 4; kc++) {
        short8 a = *(const short8*)&As[((wv * 4 + kc) * 64 + lane) * 8];
        #pragma unroll
        for (int nb = 0; nb < 8; nb++) {
            short8 bfr = *(const short8*)&Bfrag[((nb * 4 + kc) * 64 + lane) * 8];
            acc[nb] = __builtin_amdgcn_mfma_f32_16x16x32_bf16(a, bfr, acc[nb], 0, 0, 0);
        }
    }
    __syncthreads();   // done reading A-frags; reuse As as epilogue buffer

    float d[4];
    #pragma unroll
    for (int reg = 0; reg < 4; reg++) {
        int gr = r0 + wv * 16 + q * 4 + reg;
        d[reg] = (gr < N_NODES) ? dinv[gr] : 0.f;
    }
    #pragma unroll
    for (int nb = 0; nb < 8; nb++) {
        #pragma unroll
        for (int reg = 0; reg < 4; reg++) {
            int row = wv * 16 + q * 4 + reg;
            As[row * 132 + nb * 16 + m] = f2bf(acc[nb][reg] * d[reg]);
        }
    }
    __syncthreads();
    // coalesced store: thread t -> row t>>2, 32-col segment (t&3)*32 (64 B)
    {
        int row = t >> 2, segi = t & 3;
        int gr = r0 + row;
        if (gr < N_NODES) {
            const uint2* src = (const uint2*)&As[row * 132 + segi * 32];
            uint2* dst = (uint2*)&yw[(size_t)gr * F + segi * 32];
            #pragma unroll
            for (int i = 0; i < 8; i++) dst[i] = src[i];
        }
    }
}

// ---------------- 6. gather-aggregate + fused head (pre-scaled yw rows) -----------

#define EDGE_GROUP(J) {                                                      \
    u32 r = ebuf[(J) + q];                                                   \
    uint4 bb = *(const uint4*)&yw32[(size_t)r * 64 + sub * 4];               \
    pk_acc(a01, bb.x); pk_acc(a23, bb.y);                                    \
    pk_acc(a45, bb.z); pk_acc(a67, bb.w); }

#define BFLY(A) {                                                            \
    f32x2 tb;                                                                \
    tb.x = __shfl_xor(A.x, 16, 64); tb.y = __shfl_xor(A.y, 16, 64);          \
    pk_add2(A, tb);                                                          \
    tb.x = __shfl_xor(A.x, 32, 64); tb.y = __shfl_xor(A.y, 32, 64);          \
    pk_add2(A, tb); }

__global__ void k_gather(const u32* __restrict__ yw32, const u32* __restrict__ offs,
                         const u32* __restrict__ ebuf, const float* __restrict__ dinv,
                         const float* __restrict__ conv_bias, const float* __restrict__ lin_w,
                         const float* __restrict__ lin_b, float* __restrict__ out) {
    int c = blockIdx.x * 4 + (threadIdx.x >> 6);
    if (c >= N_NODES) return;
    int lane = threadIdx.x & 63;
    int q = lane >> 4, sub = lane & 15;
    u32 jbeg = offs[c], jend = offs[c + 1];
    f32x2 a01 = {0.f, 0.f}, a23 = {0.f, 0.f}, a45 = {0.f, 0.f}, a67 = {0.f, 0.f};
    u32 j = jbeg;
    for (; j + 16 <= jend; j += 16) {   // 16 edges (4 quad-groups) in flight
        EDGE_GROUP(j) EDGE_GROUP(j + 4) EDGE_GROUP(j + 8) EDGE_GROUP(j + 12)
    }
    for (; j + 4 <= jend; j += 4) EDGE_GROUP(j)
    u32 rem = jend - j;
    if (rem) {                           // 1..3 leftover edges, exec-masked adds
        u32 idx = ((u32)q < rem) ? (j + q) : j;
        u32 r = ebuf[idx];
        uint4 bb = *(const uint4*)&yw32[(size_t)r * 64 + sub * 4];
        if ((u32)q < rem) {
            pk_acc(a01, bb.x); pk_acc(a23, bb.y);
            pk_acc(a45, bb.z); pk_acc(a67, bb.w);
        }
    }
    BFLY(a01) BFLY(a23) BFLY(a45) BFLY(a67)
    float dc = dinv[c];
    uint4 sb = *(const uint4*)&yw32[(size_t)c * 64 + sub * 4];
    float4 cb0 = *(const float4*)&conv_bias[sub * 8];
    float4 cb1 = *(const float4*)&conv_bias[sub * 8 + 4];
    float4 lw0 = *(const float4*)&lin_w[sub * 8];
    float4 lw1 = *(const float4*)&lin_w[sub * 8 + 4];
    float h0 = fmaxf(dc * (a01.x + bflo(sb.x)) + cb0.x, 0.f);
    float h1 = fmaxf(dc * (a01.y + bfhi(sb.x)) + cb0.y, 0.f);
    float h2 = fmaxf(dc * (a23.x + bflo(sb.y)) + cb0.z, 0.f);
    float h3 = fmaxf(dc * (a23.y + bfhi(sb.y)) + cb0.w, 0.f);
    float h4 = fmaxf(dc * (a45.x + bflo(sb.z)) + cb1.x, 0.f);
    float h5 = fmaxf(dc * (a45.y + bfhi(sb.z)) + cb1.y, 0.f);
    float h6 = fmaxf(dc * (a67.x + bflo(sb.w)) + cb1.z, 0.f);
    float h7 = fmaxf(dc * (a67.y + bfhi(sb.w)) + cb1.w, 0.f);
    float part = (h0 * lw0.x + h1 * lw0.y + h2 * lw0.z + h3 * lw0.w)
               + (h4 * lw1.x + h5 * lw1.y + h6 * lw1.z + h7 * lw1.w);
    #pragma unroll
    for (int off = 8; off > 0; off >>= 1) part += __shfl_down(part, off, 64);
    if (lane == 0) out[c] = part + lin_b[0];
}

// ---------------- launch ----------------

extern "C" void kernel_launch(void* const* d_in, const int* in_sizes, int n_in,
                              void* d_out, int out_size, void* d_ws, size_t ws_size,
                              hipStream_t stream) {
    const float* x         = (const float*)d_in[0];
    const int*   ei        = (const int*)  d_in[1];
    const float* W         = (const float*)d_in[2];
    const float* p         = (const float*)d_in[3];
    const float* w_ih      = (const float*)d_in[4];
    const float* w_hh      = (const float*)d_in[5];
    const float* b_ih      = (const float*)d_in[6];
    const float* b_hh      = (const float*)d_in[7];
    const float* conv_bias = (const float*)d_in[8];
    const float* lin_w     = (const float*)d_in[9];
    const float* lin_b     = (const float*)d_in[10];
    float* out = (float*)d_out;

    u32*   w  = (u32*)d_ws;
    float* wf = (float*)d_ws;

    // ws layout (word offsets). G overlays PAIRS (pairs dead after k_mid).
    const size_t SCORES_W = 0;          // 100000
    const size_t DINV_W   = 100096;     // 100000
    const size_t OFFS_W   = 200192;     // 100001
    const size_t HIST16_W = 300288;     // 65536
    const size_t STATE_W  = 365824;     // 8
    const size_t GCUR_W   = 365832;     // 391 (memset covers hist16..gcur)
    const size_t BBASE_W  = 366224;     // 391 (written by k_scan16 block 1)
    const size_t CAND_W   = 366616;     // 2048
    const size_t WNEW_W   = 368920;     // 16384
    const size_t BFRAG_W  = 385304;     // 4096 words (8192 u16)
    const size_t PAIRS_W  = 389400;     // 391 * 5120 = 2001920 words
    const size_t EBUF_W   = 2400000;    // 1600000
    const size_t YW_W     = 4000000;    // bf16 yw: 6400000 words

    float* scores  = wf + SCORES_W;
    float* dinv    = wf + DINV_W;
    u32*   offs    = w  + OFFS_W;
    u32*   hist16  = w  + HIST16_W;
    u32*   state   = w  + STATE_W;
    u32*   gcur    = w  + GCUR_W;
    u32*   bbase   = w  + BBASE_W;
    u32*   cand    = w  + CAND_W;
    float* Wnew    = wf + WNEW_W;
    u16*   Bfrag   = (u16*)(w + BFRAG_W);
    u32*   pairs   = w  + PAIRS_W;
    float* G       = wf + PAIRS_W;      // overlay (pairs dead after k_mid)
    u32*   ebuf    = w  + EBUF_W;
    u16*   yw      = (u16*)(w + YW_W);
    u32*   yw32    = w + YW_W;

    hipMemsetAsync(hist16, 0, (65536 + 8 + NBUCK) * sizeof(u32), stream);

    // --- L1: edge partition (leads grid, overlaps) | scores
    k_front<<<NB_PART + NB_SCORES, 256, 0, stream>>>(x, p, ei, scores, hist16,
                                                     gcur, pairs);
    // --- L2: threshold-bucket scan | gcur prefix scan -> bbase
    k_scan16<<<2, 1024, 0, stream>>>(hist16, state, gcur, bbase);
    // --- L3: candidate collect | CSR finalize (bbase precomputed)
    k_mid<<<NB_COLLECT + NBUCK, 256, 0, stream>>>(scores, state, cand, pairs, gcur,
                                                  bbase, offs, dinv, ebuf);
    // --- GRU -> W_new (top-128 selection fused into each ggemm block)
    k_ggemm<<<dim3(4, 12), 256, 0, stream>>>(x, W, w_ih, w_hh, scores, p, state,
                                             cand, G);
    k_gate<<<64, 256, 0, stream>>>(G, W, b_ih, b_hh, Wnew, Bfrag);

    // --- yw = dinv * (x @ W_new)  (bf16 MFMA, fp32 staging)
    k_gemm<<<1563, 256, 0, stream>>>(x, Bfrag, dinv, yw);

    // --- gather + fused head
    k_gather<<<25000, 256, 0, stream>>>(yw32, offs, ebuf, dinv, conv_bias, lin_w,
                                        lin_b, out);
}